// Round 15
// baseline (317.201 us; speedup 1.0000x reference)
//
#include <hip/hip_runtime.h>

// POCACritic fused forward: B=8192, N=32, OBS=128, H=256, HEADS=4 (HD=64)
// R15 = R14 (312us best) + removal of the two mid-pipeline vmcnt(0) drains:
//  - chunk 20 issued at p=18 (slot 2 free: chunk 17 consumed@p17) -> p=19 WAITV2
//  - chunk 28 issued at p=26 (slot 1 free: chunk 25 consumed@p25) -> p=27 WAITV2,
//    with PV-seam scratch remapped to slots 0&2 (R13's as2, correctness-proven)
//    so chunk 28 survives in slot 1 until O-GEMM.
// vmcnt math: 2 loads/chunk; WAITV2 always leaves exactly the newest chunk in
// flight, so the current phase's slot is always landed.

typedef __bf16 bf16x8 __attribute__((ext_vector_type(8)));
typedef float f32x4 __attribute__((ext_vector_type(4)));
typedef unsigned short ushort_t;

#define DEVI static __device__ __forceinline__
#define MFMA16(a, b, cc) __builtin_amdgcn_mfma_f32_16x16x32_bf16((a), (b), (cc), 0, 0, 0)

#define WAITV2 asm volatile("s_waitcnt vmcnt(2)" ::: "memory")
#define WAITV0 asm volatile("s_waitcnt vmcnt(0)" ::: "memory")
#define WAITLG asm volatile("s_waitcnt lgkmcnt(0)" ::: "memory")
#define BAR() __builtin_amdgcn_s_barrier()
#define SCHEDB() __builtin_amdgcn_sched_barrier(0)

// packed-weight offsets (ushort elems). Chunk = 32-K-slice: [16 ct][64 lane][8]
constexpr int OWemb_ = 0;               // 4 chunks (K=128)
constexpr int OWq_   = 32768;           // 8 chunks each (K=256)
constexpr int OWk_   = OWq_ + 65536;
constexpr int OWv_   = OWk_ + 65536;
constexpr int OWo_   = OWv_ + 65536;
constexpr int OW1_   = OWo_ + 65536;    // tail layout [ct16][ks8][lane][8]
constexpr int OW2_   = OW1_ + 65536;

// LDS layout (bytes)
constexpr int OBS_STRIDE = 264;
constexpr int L_BST = 32768;                 // x/att frag-linear 32KB at 0
constexpr int LDS_TOTAL = 32768 + 3 * 16384; // 81920 exactly (2 blocks/CU)
static_assert(LDS_TOTAL <= 81920, "need <=80KB for 2 blocks/CU");

DEVI float silu_f(float x) { return x / (1.0f + __expf(-x)); }
DEVI f32x4 splat4(float x) { f32x4 v = {x, x, x, x}; return v; }
DEVI uint2 pack4(f32x4 v) {
  union { __bf16 h[4]; uint2 u; } x;
  x.h[0] = (__bf16)v[0]; x.h[1] = (__bf16)v[1];
  x.h[2] = (__bf16)v[2]; x.h[3] = (__bf16)v[3];
  return x.u;
}
DEVI f32x4 unpk(uint2 u) {
  union { uint2 u2; __bf16 h[4]; } x; x.u2 = u;
  f32x4 v = {(float)x.h[0], (float)x.h[1], (float)x.h[2], (float)x.h[3]};
  return v;
}
DEVI bf16x8 ld_frag(const char* p) { return *(const bf16x8*)p; }
DEVI bf16x8 u4b(unsigned a, unsigned b, unsigned cc, unsigned d) {
  union { unsigned u[4]; bf16x8 v; } x;
  x.u[0] = a; x.u[1] = b; x.u[2] = cc; x.u[3] = d;
  return x.v;
}
// explicit AGPR parking (keeps arch-VGPR pressure under the 64-reg cap)
DEVI unsigned to_agpr(unsigned v) {
  unsigned d;
  asm volatile("v_accvgpr_write_b32 %0, %1" : "=a"(d) : "v"(v));
  return d;
}
DEVI unsigned from_agpr(unsigned a) {
  unsigned d;
  asm volatile("v_accvgpr_read_b32 %0, %1" : "=v"(d) : "a"(a));
  return d;
}
// frag-linear byte offset for 4-elem group at (row, k4); k4 % 4 == 0
DEVI int xaddr(int row, int k4) {
  int t = row >> 4, cc = row & 15;
  int ks = k4 >> 5, kg = (k4 >> 3) & 3, half = (k4 >> 2) & 1;
  return ((t * 8 + ks) * 64 + kg * 16 + cc) * 16 + half * 8;
}

typedef const __attribute__((address_space(1))) unsigned int* gas_ptr;
typedef __attribute__((address_space(3))) unsigned int* las_ptr;
DEVI void gload16(const void* g, void* l) {
  __builtin_amdgcn_global_load_lds((gas_ptr)g, (las_ptr)l, 16, 0, 0);
}

// phase p -> chunk source. 0-3 emb, 4-11 Q, 12-19 K, 20-27 V, 28-35 O
constexpr int CSRC(int p) {
  return (p < 4)  ? (OWemb_ + p * 8192)
       : (p < 12) ? (OWq_ + (p - 4) * 8192)
       : (p < 20) ? (OWk_ + (p - 12) * 8192)
       : (p < 28) ? (OWv_ + (p - 20) * 8192)
                  : (OWo_ + (p - 28) * 8192);
}

DEVI void issue_chunk(const ushort_t* pw, int srcOff, char* bst, int slot, int wv, int lane) {
  char* dst = bst + slot * 16384 + wv * 2048;
  const ushort_t* s = pw + srcOff + wv * 1024 + (size_t)lane * 8;
  gload16(s, dst);
  gload16(s + 512, dst + 1024);
}
#define PH_ISSUE(ch) issue_chunk(pw, CSRC(ch), bst, (ch) % 3, wv, lane)

// ---- weight pre-pack (identical layouts to R14) ----
__global__ void pack_weights(const float* __restrict__ Wemb, const float* __restrict__ Wq,
                             const float* __restrict__ Wk, const float* __restrict__ Wv,
                             const float* __restrict__ Wo, const float* __restrict__ W1,
                             const float* __restrict__ W2, ushort_t* __restrict__ ws) {
  int t = blockIdx.x * 256 + threadIdx.x;
  if (t >= 53248) return;
  const float* src;
  int dst, n, k0;
  if (t < 4096) {                 // emb: [4ks][16ct][64l][8]
    int rem = t & 1023;
    int ctg = rem >> 6, l = rem & 63;
    n = ctg * 16 + (l & 15);
    k0 = (t >> 10) * 32 + (l >> 4) * 8;
    src = Wemb; dst = OWemb_ + t * 8;
  } else if (t < 36864) {         // q,k,v,o: [8ks][16ct][64l][8]
    int u = t - 4096, m = u >> 13, loc = u & 8191;
    int rem = loc & 1023;
    int ctg = rem >> 6, l = rem & 63;
    n = ctg * 16 + (l & 15);
    k0 = (loc >> 10) * 32 + (l >> 4) * 8;
    src = (m == 0) ? Wq : (m == 1) ? Wk : (m == 2) ? Wv : Wo;
    dst = OWq_ + m * 65536 + loc * 8;
  } else {                        // W1,W2 (tail): [ct16][ks8][lane][8]
    int u = t - 36864, m = u >> 13, loc = u & 8191;
    int ln = loc & 63, ks = (loc >> 6) & 7, ct = loc >> 9;
    n = ct * 16 + (ln & 15);
    k0 = ks * 32 + (ln >> 4) * 8;
    src = m ? W2 : W1; dst = OW1_ + m * 65536 + loc * 8;
  }
  union { __bf16 h[8]; uint4 u; } pk;
  #pragma unroll
  for (int j = 0; j < 8; ++j) pk.h[j] = (__bf16)src[(k0 + j) * 256 + n];
  *(uint4*)(ws + dst) = pk.u;
}

__global__ __launch_bounds__(512, 4)
void poca_fused(const float* __restrict__ obs, const ushort_t* __restrict__ pw,
                const float* __restrict__ b_emb, const float* __restrict__ bq,
                const float* __restrict__ bk, const float* __restrict__ bv,
                const float* __restrict__ bo, const float* __restrict__ b1,
                const float* __restrict__ b2, const float* __restrict__ Wval,
                const float* __restrict__ bval, float* __restrict__ out) {
  __shared__ __align__(128) char lds[LDS_TOTAL];
  const int tid = threadIdx.x;
  const int wv = tid >> 6, lane = tid & 63;
  const int g = lane >> 4, c = lane & 15;
  const int mg = wv >> 2, ng = wv & 3;       // wave = (batch mg, head/ncols ng)
  char* xb = lds;                            // obs (row-major 264) -> x -> att (frag-linear)
  char* bst = lds + L_BST;                   // 3 x 16KB staging slots
  char* as_ = bst + wv * 4096;               // S-seam scratch: slots 0-1 (drained)
  char* as2 = (wv < 4) ? (bst + wv * 4096) : (bst + 32768 + (wv - 4) * 4096); // PV: slots 0&2
  char* pp1 = bst;                           // LN1 partials: slot 0 free at LN1
  char* poolb = bst;                         // tail overlays (all staging dead)
  char* y1b = bst + 8448;
  char* ptlb = bst + 16896;
  char* pp2 = bst + 20480;                   // LN2 partials

  PH_ISSUE(0); PH_ISSUE(1);
  // emb bias preload (before further issues; consumed at phase 0)
  f32x4 bemb_r[4];
  #pragma unroll
  for (int ct = 0; ct < 4; ++ct) bemb_r[ct] = *(const f32x4*)(b_emb + ng * 64 + ct * 16 + g * 4);

  // ---- stage obs: 64 rows x 128 f32 -> bf16 row-major stride 264 ----
  {
    const float4* op = (const float4*)(obs + (size_t)blockIdx.x * 64 * 128);
    #pragma unroll
    for (int it = 0; it < 4; ++it) {
      int idx = it * 512 + tid;              // 0..2047
      float4 v = op[idx];
      int row = idx >> 5, col4 = idx & 31;
      union { __bf16 h[4]; uint2 u; } cv;
      cv.h[0] = (__bf16)v.x; cv.h[1] = (__bf16)v.y;
      cv.h[2] = (__bf16)v.z; cv.h[3] = (__bf16)v.w;
      *(uint2*)(xb + row * OBS_STRIDE + col4 * 8) = cv.u;
    }
  }
  WAITLG;

  f32x4 acc[2][4];

  // ===== emb: phases 0..3 (single barrier; issue p+2 AFTER barrier) =====
  #pragma unroll
  for (int p = 0; p < 4; ++p) {
    WAITV2; BAR();
    PH_ISSUE(p + 2);                        // chunks 2..5
    if (p == 0) {
      #pragma unroll
      for (int ct = 0; ct < 4; ++ct) { acc[0][ct] = bemb_r[ct]; acc[1][ct] = bemb_r[ct]; }
    }
    const char* ck = bst + (p % 3) * 16384;
    bf16x8 wf[4], xf[2];
    #pragma unroll
    for (int t = 0; t < 4; ++t) wf[t] = ld_frag(ck + ((ng * 4 + t) * 64 + lane) * 16);
    #pragma unroll
    for (int rt = 0; rt < 2; ++rt)
      xf[rt] = ld_frag(xb + ((mg * 2 + rt) * 16 + c) * OBS_STRIDE + p * 64 + g * 16);
    #pragma unroll
    for (int rt = 0; rt < 2; ++rt)
      #pragma unroll
      for (int ct = 0; ct < 4; ++ct) acc[rt][ct] = MFMA16(wf[ct], xf[rt], acc[rt][ct]);
    SCHEDB();
  }

  // ---- LN1: partials in slot 0 (free: c3 consumed, c6 issued later) ----
  BAR();                                     // phase-3 reads serviced (SCHEDB pin)
  #pragma unroll
  for (int rt = 0; rt < 2; ++rt)
    #pragma unroll
    for (int ct = 0; ct < 4; ++ct)
      #pragma unroll
      for (int r = 0; r < 4; ++r) acc[rt][ct][r] = silu_f(acc[rt][ct][r]);
  #pragma unroll
  for (int rt = 0; rt < 2; ++rt) {
    float s1 = 0.f, s2 = 0.f;
    #pragma unroll
    for (int ct = 0; ct < 4; ++ct)
      #pragma unroll
      for (int r = 0; r < 4; ++r) { float e = acc[rt][ct][r]; s1 += e; s2 += e * e; }
    s1 += __shfl_xor(s1, 16); s2 += __shfl_xor(s2, 16);
    s1 += __shfl_xor(s1, 32); s2 += __shfl_xor(s2, 32);
    if (g == 0)
      *(float2*)(pp1 + (mg * 32 + rt * 16 + c) * 32 + ng * 8) = make_float2(s1, s2);
  }
  WAITLG; BAR();
  {
    float mu[2], rs[2];
    #pragma unroll
    for (int rt = 0; rt < 2; ++rt) {
      int row = mg * 32 + rt * 16 + c;
      f32x4 pA = *(const f32x4*)(pp1 + row * 32);
      f32x4 pB = *(const f32x4*)(pp1 + row * 32 + 16);
      float S1 = pA[0] + pA[2] + pB[0] + pB[2];
      float S2 = pA[1] + pA[3] + pB[1] + pB[3];
      float m_ = S1 * (1.f / 256.f);
      float v_ = S2 * (1.f / 256.f) - m_ * m_;
      mu[rt] = m_; rs[rt] = rsqrtf(v_ + 1e-5f);
    }
    #pragma unroll
    for (int rt = 0; rt < 2; ++rt)
      #pragma unroll
      for (int ct = 0; ct < 4; ++ct) {
        f32x4 xv;
        #pragma unroll
        for (int r = 0; r < 4; ++r) xv[r] = (acc[rt][ct][r] - mu[rt]) * rs[rt];
        *(uint2*)(xb + xaddr(mg * 32 + rt * 16 + c, ng * 64 + ct * 16 + g * 4)) = pack4(xv);
      }
  }
  // Q bias preload before Q-section issues
  f32x4 bq_r[4];
  #pragma unroll
  for (int ct = 0; ct < 4; ++ct) bq_r[ct] = *(const f32x4*)(bq + ng * 64 + ct * 16 + g * 4);
  SCHEDB();
  WAITLG; BAR();

  // ===== Q-GEMM: phases 4..11 =====
  #pragma unroll
  for (int p = 4; p < 12; ++p) {
    WAITV2; BAR();
    PH_ISSUE(p + 2);                        // chunks 6..13
    if (p == 4) {
      #pragma unroll
      for (int ct = 0; ct < 4; ++ct) { acc[0][ct] = bq_r[ct]; acc[1][ct] = bq_r[ct]; }
    }
    const char* ck = bst + (p % 3) * 16384;
    const int ks = p - 4;
    bf16x8 wf[4], xf[2];
    #pragma unroll
    for (int t = 0; t < 4; ++t) wf[t] = ld_frag(ck + ((ng * 4 + t) * 64 + lane) * 16);
    #pragma unroll
    for (int rt = 0; rt < 2; ++rt)
      xf[rt] = ld_frag(xb + (((mg * 2 + rt) * 8 + ks) * 64 + lane) * 16);
    #pragma unroll
    for (int rt = 0; rt < 2; ++rt)
      #pragma unroll
      for (int ct = 0; ct < 4; ++ct) acc[rt][ct] = MFMA16(wf[ct], xf[rt], acc[rt][ct]);
    SCHEDB();
  }

  // park q in AGPRs; K bias preload
  unsigned qs[16];
  #pragma unroll
  for (int rt = 0; rt < 2; ++rt)
    #pragma unroll
    for (int ct = 0; ct < 4; ++ct) {
      uint2 qp = pack4(acc[rt][ct]);
      qs[(rt * 4 + ct) * 2] = to_agpr(qp.x);
      qs[(rt * 4 + ct) * 2 + 1] = to_agpr(qp.y);
    }
  f32x4 bk_r[4];
  #pragma unroll
  for (int ct = 0; ct < 4; ++ct) bk_r[ct] = *(const f32x4*)(bk + ng * 64 + ct * 16 + g * 4);

  // ===== K-GEMM: phases 12..19 (issue through p=18 -> chunk 20; no drain) =====
  #pragma unroll
  for (int p = 12; p < 20; ++p) {
    WAITV2; BAR();
    if (p <= 18) PH_ISSUE(p + 2);           // chunks 14..20 (20 -> slot 2, safe)
    if (p == 12) {
      #pragma unroll
      for (int ct = 0; ct < 4; ++ct) { acc[0][ct] = bk_r[ct]; acc[1][ct] = bk_r[ct]; }
    }
    const char* ck = bst + (p % 3) * 16384;
    const int ks = p - 12;
    bf16x8 wf[4], xf[2];
    #pragma unroll
    for (int t = 0; t < 4; ++t) wf[t] = ld_frag(ck + ((ng * 4 + t) * 64 + lane) * 16);
    #pragma unroll
    for (int rt = 0; rt < 2; ++rt)
      xf[rt] = ld_frag(xb + (((mg * 2 + rt) * 8 + ks) * 64 + lane) * 16);
    #pragma unroll
    for (int rt = 0; rt < 2; ++rt)
      #pragma unroll
      for (int ct = 0; ct < 4; ++ct) acc[rt][ct] = MFMA16(wf[ct], xf[rt], acc[rt][ct]);
    SCHEDB();
  }

  // ===== S^T + softmax seam (scratch slots 0-1; chunk 20 already in flight) =====
  uint2 p_pk[2][2];
  float bv_r[4];
  {
    BAR();                                   // phase-19 reads serviced (SCHEDB pin)
    f32x4 sacc[2][2];
    sacc[0][0] = splat4(0.f); sacc[0][1] = splat4(0.f);
    sacc[1][0] = splat4(0.f); sacc[1][1] = splat4(0.f);
    #pragma unroll
    for (int hf = 0; hf < 2; ++hf) {
      #pragma unroll
      for (int rt2 = 0; rt2 < 2; ++rt2)
        #pragma unroll
        for (int ctl = 0; ctl < 2; ++ctl) {
          int gr = ctl * 2 + (g >> 1);
          int off = rt2 * 1024 + (gr * 16 + c) * 16 + (g & 1) * 8;
          int qi = (rt2 * 4 + hf * 2 + ctl) * 2;
          *(uint2*)(as_ + off) = make_uint2(from_agpr(qs[qi]), from_agpr(qs[qi + 1]));
          *(uint2*)(as_ + 2048 + off) = pack4(acc[rt2][hf * 2 + ctl]);
        }
      WAITLG;
      bf16x8 qf[2], kf[2];
      #pragma unroll
      for (int t = 0; t < 2; ++t) {
        qf[t] = ld_frag(as_ + t * 1024 + lane * 16);
        kf[t] = ld_frag(as_ + 2048 + t * 1024 + lane * 16);
      }
      #pragma unroll
      for (int qt = 0; qt < 2; ++qt)
        #pragma unroll
        for (int kt = 0; kt < 2; ++kt)
          sacc[qt][kt] = MFMA16(kf[kt], qf[qt], sacc[qt][kt]);   // S^T
    }
    #pragma unroll
    for (int qt = 0; qt < 2; ++qt) {
      float sc[2][4];
      float mx = -3e38f;
      #pragma unroll
      for (int kt = 0; kt < 2; ++kt)
        #pragma unroll
        for (int r = 0; r < 4; ++r) { sc[kt][r] = sacc[qt][kt][r] * 0.125f; mx = fmaxf(mx, sc[kt][r]); }
      mx = fmaxf(mx, __shfl_xor(mx, 16));
      mx = fmaxf(mx, __shfl_xor(mx, 32));
      float sm = 0.f;
      #pragma unroll
      for (int kt = 0; kt < 2; ++kt)
        #pragma unroll
        for (int r = 0; r < 4; ++r) { float e = __expf(sc[kt][r] - mx); sc[kt][r] = e; sm += e; }
      sm += __shfl_xor(sm, 16);
      sm += __shfl_xor(sm, 32);
      float ri = 1.0f / sm;                  // fold into P: PV needs no rescale
      #pragma unroll
      for (int kt = 0; kt < 2; ++kt) {
        f32x4 pv = {sc[kt][0] * ri, sc[kt][1] * ri, sc[kt][2] * ri, sc[kt][3] * ri};
        p_pk[qt][kt] = pack4(pv);
      }
    }
    // V bias preload (scalar per ct; x-as-A orientation)
    #pragma unroll
    for (int ct = 0; ct < 4; ++ct) bv_r[ct] = bv[ng * 64 + ct * 16 + c];
  }
  SCHEDB();
  WAITLG; BAR();                             // scratch reads serviced; staging restart
  PH_ISSUE(21);

  // ===== V-GEMM: phases 20..27 (x-as-A; issue through p=26 -> chunk 28) =====
  #pragma unroll
  for (int p = 20; p < 28; ++p) {
    WAITV2; BAR();
    if (p <= 26) PH_ISSUE(p + 2);           // chunks 22..28 (28 -> slot 1, safe)
    if (p == 20) {
      #pragma unroll
      for (int ct = 0; ct < 4; ++ct) {
        f32x4 b_ = splat4(bv_r[ct]);
        acc[0][ct] = b_; acc[1][ct] = b_;
      }
    }
    const char* ck = bst + (p % 3) * 16384;
    const int ks = p - 20;
    bf16x8 wf[4], xf[2];
    #pragma unroll
    for (int t = 0; t < 4; ++t) wf[t] = ld_frag(ck + ((ng * 4 + t) * 64 + lane) * 16);
    #pragma unroll
    for (int rt = 0; rt < 2; ++rt)
      xf[rt] = ld_frag(xb + (((mg * 2 + rt) * 8 + ks) * 64 + lane) * 16);
    #pragma unroll
    for (int rt = 0; rt < 2; ++rt)
      #pragma unroll
      for (int ct = 0; ct < 4; ++ct) acc[rt][ct] = MFMA16(xf[rt], wf[ct], acc[rt][ct]);
    SCHEDB();
  }

  // ===== PV + att store + O-init seam (scratch slots 0&2; chunk 28 lives in slot 1) =====
  {
    BAR();                                   // phase-27 reads serviced
    // vT frag-linear straight from V accumulator
    #pragma unroll
    for (int rt2 = 0; rt2 < 2; ++rt2)
      #pragma unroll
      for (int ct = 0; ct < 4; ++ct) {
        int gr = rt2 * 2 + (g >> 1);
        int off = ct * 1024 + (gr * 16 + c) * 16 + (g & 1) * 8;
        *(uint2*)(as2 + off) = pack4(acc[rt2][ct]);
      }
    // residual x re-read (own disjoint region; BEFORE own att writes)
    uint2 respk[2][4];
    #pragma unroll
    for (int rt = 0; rt < 2; ++rt)
      #pragma unroll
      for (int ct = 0; ct < 4; ++ct)
        respk[rt][ct] = *(uint2*)(xb + xaddr(mg * 32 + rt * 16 + c, ng * 64 + ct * 16 + g * 4));
    WAITLG;
    bf16x8 vf[4];
    #pragma unroll
    for (int dt = 0; dt < 4; ++dt) vf[dt] = ld_frag(as2 + dt * 1024 + lane * 16);
    const int l1 = (g & 1) * 32 + c, l2 = l1 + 16;
    const bool hi = (g >= 2);
    #pragma unroll
    for (int qt = 0; qt < 2; ++qt) {
      unsigned x0k0 = __shfl(p_pk[qt][0].x, l1), x0k1 = __shfl(p_pk[qt][1].x, l1);
      unsigned y0k0 = __shfl(p_pk[qt][0].y, l1), y0k1 = __shfl(p_pk[qt][1].y, l1);
      unsigned x1k0 = __shfl(p_pk[qt][0].x, l2), x1k1 = __shfl(p_pk[qt][1].x, l2);
      unsigned y1k0 = __shfl(p_pk[qt][0].y, l2), y1k1 = __shfl(p_pk[qt][1].y, l2);
      bf16x8 pf = u4b(hi ? x0k1 : x0k0, hi ? y0k1 : y0k0, hi ? x1k1 : x1k0, hi ? y1k1 : y1k0);
      #pragma unroll
      for (int dt = 0; dt < 4; ++dt) {
        f32x4 o = splat4(0.f);
        o = MFMA16(vf[dt], pf, o);           // P pre-scaled: no rescale
        *(uint2*)(xb + xaddr(mg * 32 + qt * 16 + c, ng * 64 + dt * 16 + g * 4)) = pack4(o);
      }
    }
    // O bias loaded AFTER PV (cuts seam peak live); O-GEMM C-init
    f32x4 bo_r[4];
    #pragma unroll
    for (int ct = 0; ct < 4; ++ct) bo_r[ct] = *(const f32x4*)(bo + ng * 64 + ct * 16 + g * 4);
    #pragma unroll
    for (int ct = 0; ct < 4; ++ct) {
      #pragma unroll
      for (int rt = 0; rt < 2; ++rt) acc[rt][ct] = bo_r[ct] + unpk(respk[rt][ct]);
    }
  }
  SCHEDB();
  WAITLG; BAR();
  PH_ISSUE(29);

  // ===== O-GEMM: phases 28..35 (issue p+2 for p<=33) =====
  #pragma unroll
  for (int p = 28; p < 36; ++p) {
    if (p < 35) { WAITV2; } else { WAITV0; }
    BAR();
    if (p <= 33) PH_ISSUE(p + 2);           // chunks 30..35
    const char* ck = bst + (p % 3) * 16384;
    const int ks = p - 28;
    bf16x8 wf[4], xf[2];
    #pragma unroll
    for (int t = 0; t < 4; ++t) wf[t] = ld_frag(ck + ((ng * 4 + t) * 64 + lane) * 16);
    #pragma unroll
    for (int rt = 0; rt < 2; ++rt)
      xf[rt] = ld_frag(xb + (((mg * 2 + rt) * 8 + ks) * 64 + lane) * 16);
    #pragma unroll
    for (int rt = 0; rt < 2; ++rt)
      #pragma unroll
      for (int ct = 0; ct < 4; ++ct) acc[rt][ct] = MFMA16(wf[ct], xf[rt], acc[rt][ct]);
    SCHEDB();
  }

  // ---- LN2 + pool (partials pp2 in dead staging) ----
  BAR();                                     // phase-35 reads serviced
  #pragma unroll
  for (int rt = 0; rt < 2; ++rt) {
    float s1 = 0.f, s2 = 0.f;
    #pragma unroll
    for (int ct = 0; ct < 4; ++ct)
      #pragma unroll
      for (int r = 0; r < 4; ++r) { float e = acc[rt][ct][r]; s1 += e; s2 += e * e; }
    s1 += __shfl_xor(s1, 16); s2 += __shfl_xor(s2, 16);
    s1 += __shfl_xor(s1, 32); s2 += __shfl_xor(s2, 32);
    if (g == 0)
      *(float2*)(pp2 + (mg * 32 + rt * 16 + c) * 32 + ng * 8) = make_float2(s1, s2);
  }
  WAITLG; BAR();
  {
    float mu[2], rs[2];
    #pragma unroll
    for (int rt = 0; rt < 2; ++rt) {
      int row = mg * 32 + rt * 16 + c;
      f32x4 pA = *(const f32x4*)(pp2 + row * 32);
      f32x4 pB = *(const f32x4*)(pp2 + row * 32 + 16);
      float S1 = pA[0] + pA[2] + pB[0] + pB[2];
      float S2 = pA[1] + pA[3] + pB[1] + pB[3];
      float m_ = S1 * (1.f / 256.f);
      float v_ = S2 * (1.f / 256.f) - m_ * m_;
      mu[rt] = m_; rs[rt] = rsqrtf(v_ + 1e-5f);
    }
    f32x4 ps[4];
    #pragma unroll
    for (int ct = 0; ct < 4; ++ct) {
      #pragma unroll
      for (int r = 0; r < 4; ++r)
        ps[ct][r] = (acc[0][ct][r] - mu[0]) * rs[0] + (acc[1][ct][r] - mu[1]) * rs[1];
    }
    #pragma unroll
    for (int st = 1; st < 16; st <<= 1)
      #pragma unroll
      for (int ct = 0; ct < 4; ++ct)
        #pragma unroll
        for (int r = 0; r < 4; ++r) ps[ct][r] += __shfl_xor(ps[ct][r], st);
    if (c == 0) {
      #pragma unroll
      for (int ct = 0; ct < 4; ++ct) {
        f32x4 pv;
        #pragma unroll
        for (int r = 0; r < 4; ++r) pv[r] = ps[ct][r] * (1.f / 32.f);
        *(uint2*)(poolb + mg * 528 + (ng * 64 + ct * 16 + g * 4) * 2) = pack4(pv);
      }
    }
  }
  // zero pool/y1 rows 2..15 (cols 0..255)
  #pragma unroll
  for (int it = 0; it < 4; ++it) {
    int idx = it * 512 + tid;
    if (idx < 1792) {
      int row = 2 + (idx >> 7), col = idx & 127;
      *(unsigned*)(poolb + row * 528 + col * 4) = 0;
      *(unsigned*)(y1b + row * 528 + col * 4) = 0;
    }
  }
  WAITLG; BAR();

  // ===== tail MLP: M=16 MFMA (2 valid rows); wave wv owns cols wv*32..+31 =====
  f32x4 t1[2];
  #pragma unroll
  for (int ctl = 0; ctl < 2; ++ctl) t1[ctl] = splat4(b1[wv * 32 + ctl * 16 + c]);
  #pragma unroll
  for (int ks = 0; ks < 8; ++ks) {
    bf16x8 a = ld_frag(poolb + c * 528 + ks * 64 + g * 16);
    #pragma unroll
    for (int ctl = 0; ctl < 2; ++ctl) {
      bf16x8 b = *(const bf16x8*)(pw + OW1_ + (size_t)(((wv * 2 + ctl) * 8 + ks) * 64 + lane) * 8);
      t1[ctl] = MFMA16(a, b, t1[ctl]);
    }
  }
  if (g == 0) {
    #pragma unroll
    for (int ctl = 0; ctl < 2; ++ctl)
      #pragma unroll
      for (int r = 0; r < 4; ++r)
        *(__bf16*)(y1b + r * 528 + (wv * 32 + ctl * 16 + c) * 2) = (__bf16)silu_f(t1[ctl][r]);
  }
  WAITLG; BAR();
  f32x4 t2[2];
  #pragma unroll
  for (int ctl = 0; ctl < 2; ++ctl) t2[ctl] = splat4(b2[wv * 32 + ctl * 16 + c]);
  #pragma unroll
  for (int ks = 0; ks < 8; ++ks) {
    bf16x8 a = ld_frag(y1b + c * 528 + ks * 64 + g * 16);
    #pragma unroll
    for (int ctl = 0; ctl < 2; ++ctl) {
      bf16x8 b = *(const bf16x8*)(pw + OW2_ + (size_t)(((wv * 2 + ctl) * 8 + ks) * 64 + lane) * 8);
      t2[ctl] = MFMA16(a, b, t2[ctl]);
    }
  }
  if (g == 0) {
    float part[4] = {0.f, 0.f, 0.f, 0.f};
    #pragma unroll
    for (int ctl = 0; ctl < 2; ++ctl) {
      float wvv = Wval[wv * 32 + ctl * 16 + c];
      #pragma unroll
      for (int r = 0; r < 4; ++r) part[r] += silu_f(t2[ctl][r]) * wvv;
    }
    #pragma unroll
    for (int m = 1; m < 16; m <<= 1) {
      #pragma unroll
      for (int r = 0; r < 4; ++r) part[r] += __shfl_xor(part[r], m);
    }
    if (c == 0) {
      float4 p4 = make_float4(part[0], part[1], part[2], part[3]);
      *(float4*)(ptlb + wv * 16) = p4;
    }
  }
  WAITLG; BAR();
  if (tid < 2) {
    float s = Wval[256] + bval[0];
    const float* pt = (const float*)ptlb;
    #pragma unroll
    for (int w8 = 0; w8 < 8; ++w8) s += pt[w8 * 4 + tid];
    out[(size_t)blockIdx.x * 2 + tid] = s;
  }
}

extern "C" void kernel_launch(void* const* d_in, const int* in_sizes, int n_in,
                              void* d_out, int out_size, void* d_ws, size_t ws_size,
                              hipStream_t stream) {
  (void)in_sizes; (void)n_in; (void)out_size; (void)ws_size;
  const float* obs  = (const float*)d_in[0];
  const float* Wemb = (const float*)d_in[1];
  const float* bemb = (const float*)d_in[2];
  const float* Wq   = (const float*)d_in[3];
  const float* bq   = (const float*)d_in[4];
  const float* Wk   = (const float*)d_in[5];
  const float* bk   = (const float*)d_in[6];
  const float* Wv   = (const float*)d_in[7];
  const float* bv   = (const float*)d_in[8];
  const float* Wo   = (const float*)d_in[9];
  const float* bo   = (const float*)d_in[10];
  const float* W1   = (const float*)d_in[11];
  const float* b1   = (const float*)d_in[12];
  const float* W2   = (const float*)d_in[13];
  const float* b2   = (const float*)d_in[14];
  const float* Wval = (const float*)d_in[15];
  const float* bval = (const float*)d_in[16];
  ushort_t* ws = (ushort_t*)d_ws;
  float* out = (float*)d_out;

  pack_weights<<<208, 256, 0, stream>>>(Wemb, Wq, Wk, Wv, Wo, W1, W2, ws);
  poca_fused<<<4096, 512, 0, stream>>>(obs, ws, bemb, bq, bk, bv, bo, b1, b2, Wval, bval, out);
}

// Round 16
// 295.298 us; speedup vs baseline: 1.0742x; 1.0742x over previous
//
#include <hip/hip_runtime.h>

// POCACritic fused forward: B=8192, N=32, OBS=128, H=256, HEADS=4 (HD=64)
// R16: staging-free restructure. Weights load straight from L2 into registers
// (4x global_load_dwordx4 per phase per wave; each wave reads only its ng
// quarter; L2-resident 851KB packed weights). No per-phase barriers, no
// vmcnt juggling -- sections are straight-line, compiler-pipelined. Barriers
// only at true cross-wave x-buffer hazards (~10 total vs ~40). Seam scratch
// is wave-private (S-seam needs NO barrier). LDS = 32K x + 32K scratch/tail
// + 2K partials = 67.6KB -> 2 blocks/CU. (512,4) + arch<=64 discipline kept.

typedef __bf16 bf16x8 __attribute__((ext_vector_type(8)));
typedef float f32x4 __attribute__((ext_vector_type(4)));
typedef unsigned short ushort_t;

#define DEVI static __device__ __forceinline__
#define MFMA16(a, b, cc) __builtin_amdgcn_mfma_f32_16x16x32_bf16((a), (b), (cc), 0, 0, 0)

#define WAITLG asm volatile("s_waitcnt lgkmcnt(0)" ::: "memory")
#define BAR() __builtin_amdgcn_s_barrier()
#define SCHEDB() __builtin_amdgcn_sched_barrier(0)

// packed-weight offsets (ushort elems). [Kks][16ct][64l][8]: ks-stride 8192,
// ct-stride 512 (ushorts).
constexpr int OWemb_ = 0;               // 4 ks (K=128)
constexpr int OWq_   = 32768;           // 8 ks each (K=256)
constexpr int OWk_   = OWq_ + 65536;
constexpr int OWv_   = OWk_ + 65536;
constexpr int OWo_   = OWv_ + 65536;
constexpr int OW1_   = OWo_ + 65536;    // tail layout [ct16][ks8][lane][8]
constexpr int OW2_   = OW1_ + 65536;

// LDS layout (bytes)
constexpr int OBS_STRIDE = 264;
constexpr int L_SCR = 32768;              // x/att frag-linear 32KB at 0
constexpr int L_PP  = 65536;              // 8 waves x 4KB wave-private scratch / tail overlay
constexpr int LDS_TOTAL = 65536 + 2048;   // partials f32 [64 rows][32B]
static_assert(LDS_TOTAL <= 81920, "need <=80KB for 2 blocks/CU");

DEVI float silu_f(float x) { return x / (1.0f + __expf(-x)); }
DEVI f32x4 splat4(float x) { f32x4 v = {x, x, x, x}; return v; }
DEVI uint2 pack4(f32x4 v) {
  union { __bf16 h[4]; uint2 u; } x;
  x.h[0] = (__bf16)v[0]; x.h[1] = (__bf16)v[1];
  x.h[2] = (__bf16)v[2]; x.h[3] = (__bf16)v[3];
  return x.u;
}
DEVI f32x4 unpk(uint2 u) {
  union { uint2 u2; __bf16 h[4]; } x; x.u2 = u;
  f32x4 v = {(float)x.h[0], (float)x.h[1], (float)x.h[2], (float)x.h[3]};
  return v;
}
DEVI bf16x8 ld_frag(const char* p) { return *(const bf16x8*)p; }
DEVI bf16x8 ld_fragg(const ushort_t* p) { return *(const bf16x8*)p; }
DEVI bf16x8 u4b(unsigned a, unsigned b, unsigned cc, unsigned d) {
  union { unsigned u[4]; bf16x8 v; } x;
  x.u[0] = a; x.u[1] = b; x.u[2] = cc; x.u[3] = d;
  return x.v;
}
// explicit AGPR parking (keeps arch-VGPR pressure under the 64-reg cap)
DEVI unsigned to_agpr(unsigned v) {
  unsigned d;
  asm volatile("v_accvgpr_write_b32 %0, %1" : "=a"(d) : "v"(v));
  return d;
}
DEVI unsigned from_agpr(unsigned a) {
  unsigned d;
  asm volatile("v_accvgpr_read_b32 %0, %1" : "=v"(d) : "a"(a));
  return d;
}
// frag-linear byte offset for 4-elem group at (row, k4); k4 % 4 == 0
DEVI int xaddr(int row, int k4) {
  int t = row >> 4, cc = row & 15;
  int ks = k4 >> 5, kg = (k4 >> 3) & 3, half = (k4 >> 2) & 1;
  return ((t * 8 + ks) * 64 + kg * 16 + cc) * 16 + half * 8;
}

// ---- weight pre-pack (identical layouts to R14) ----
__global__ void pack_weights(const float* __restrict__ Wemb, const float* __restrict__ Wq,
                             const float* __restrict__ Wk, const float* __restrict__ Wv,
                             const float* __restrict__ Wo, const float* __restrict__ W1,
                             const float* __restrict__ W2, ushort_t* __restrict__ ws) {
  int t = blockIdx.x * 256 + threadIdx.x;
  if (t >= 53248) return;
  const float* src;
  int dst, n, k0;
  if (t < 4096) {                 // emb: [4ks][16ct][64l][8]
    int rem = t & 1023;
    int ctg = rem >> 6, l = rem & 63;
    n = ctg * 16 + (l & 15);
    k0 = (t >> 10) * 32 + (l >> 4) * 8;
    src = Wemb; dst = OWemb_ + t * 8;
  } else if (t < 36864) {         // q,k,v,o: [8ks][16ct][64l][8]
    int u = t - 4096, m = u >> 13, loc = u & 8191;
    int rem = loc & 1023;
    int ctg = rem >> 6, l = rem & 63;
    n = ctg * 16 + (l & 15);
    k0 = (loc >> 10) * 32 + (l >> 4) * 8;
    src = (m == 0) ? Wq : (m == 1) ? Wk : (m == 2) ? Wv : Wo;
    dst = OWq_ + m * 65536 + loc * 8;
  } else {                        // W1,W2 (tail): [ct16][ks8][lane][8]
    int u = t - 36864, m = u >> 13, loc = u & 8191;
    int ln = loc & 63, ks = (loc >> 6) & 7, ct = loc >> 9;
    n = ct * 16 + (ln & 15);
    k0 = ks * 32 + (ln >> 4) * 8;
    src = m ? W2 : W1; dst = OW1_ + m * 65536 + loc * 8;
  }
  union { __bf16 h[8]; uint4 u; } pk;
  #pragma unroll
  for (int j = 0; j < 8; ++j) pk.h[j] = (__bf16)src[(k0 + j) * 256 + n];
  *(uint4*)(ws + dst) = pk.u;
}

__global__ __launch_bounds__(512, 4)
void poca_fused(const float* __restrict__ obs, const ushort_t* __restrict__ pw,
                const float* __restrict__ b_emb, const float* __restrict__ bq,
                const float* __restrict__ bk, const float* __restrict__ bv,
                const float* __restrict__ bo, const float* __restrict__ b1,
                const float* __restrict__ b2, const float* __restrict__ Wval,
                const float* __restrict__ bval, float* __restrict__ out) {
  __shared__ __align__(128) char lds[LDS_TOTAL];
  const int tid = threadIdx.x;
  const int wv = tid >> 6, lane = tid & 63;
  const int g = lane >> 4, c = lane & 15;
  const int mg = wv >> 2, ng = wv & 3;       // wave = (batch mg, head/ncols ng)
  char* xb = lds;                            // obs (row-major 264) -> x -> att (frag-linear)
  char* scr = lds + L_SCR;
  char* as_ = scr + wv * 4096;               // wave-private seam scratch
  char* ppb = lds + L_PP;                    // cross-wave LN partials
  char* poolb = scr;                         // tail overlays scratch (dead)
  char* y1b = scr + 8448;
  char* ptlb = scr + 16896;

  // per-wave weight fragment base (this wave's ng quarter); ushort offsets:
  // (ks, t, lane) -> ks*8192 + t*512 + lane*8
  const size_t wqoff = (size_t)((ng * 4) * 64 + lane) * 8;

  // emb bias preload
  f32x4 bemb_r[4];
  #pragma unroll
  for (int ct = 0; ct < 4; ++ct) bemb_r[ct] = *(const f32x4*)(b_emb + ng * 64 + ct * 16 + g * 4);

  // ---- stage obs: 64 rows x 128 f32 -> bf16 row-major stride 264 ----
  {
    const float4* op = (const float4*)(obs + (size_t)blockIdx.x * 64 * 128);
    #pragma unroll
    for (int it = 0; it < 4; ++it) {
      int idx = it * 512 + tid;              // 0..2047
      float4 v = op[idx];
      int row = idx >> 5, col4 = idx & 31;
      union { __bf16 h[4]; uint2 u; } cv;
      cv.h[0] = (__bf16)v.x; cv.h[1] = (__bf16)v.y;
      cv.h[2] = (__bf16)v.z; cv.h[3] = (__bf16)v.w;
      *(uint2*)(xb + row * OBS_STRIDE + col4 * 8) = cv.u;
    }
  }
  WAITLG; BAR();                             // obs visible to all waves

  f32x4 acc[2][4];

  // ===== emb: ent = silu(obs @ Wemb + b_emb), K=128, 4 phases straight-line =====
  {
    const ushort_t* wsec = pw + OWemb_ + wqoff;
    #pragma unroll
    for (int ct = 0; ct < 4; ++ct) { acc[0][ct] = bemb_r[ct]; acc[1][ct] = bemb_r[ct]; }
    #pragma unroll
    for (int p = 0; p < 4; ++p) {
      bf16x8 wf[4], xf[2];
      #pragma unroll
      for (int t = 0; t < 4; ++t) wf[t] = ld_fragg(wsec + p * 8192 + t * 512);
      #pragma unroll
      for (int rt = 0; rt < 2; ++rt)
        xf[rt] = ld_frag(xb + ((mg * 2 + rt) * 16 + c) * OBS_STRIDE + p * 64 + g * 16);
      #pragma unroll
      for (int rt = 0; rt < 2; ++rt)
        #pragma unroll
        for (int ct = 0; ct < 4; ++ct) acc[rt][ct] = MFMA16(wf[ct], xf[rt], acc[rt][ct]);
    }
  }
  SCHEDB();                                  // pin emb MFMAs (obs reads serviced)

  // ---- silu + LN1 -> x frag-linear ----
  #pragma unroll
  for (int rt = 0; rt < 2; ++rt)
    #pragma unroll
    for (int ct = 0; ct < 4; ++ct)
      #pragma unroll
      for (int r = 0; r < 4; ++r) acc[rt][ct][r] = silu_f(acc[rt][ct][r]);
  #pragma unroll
  for (int rt = 0; rt < 2; ++rt) {
    float s1 = 0.f, s2 = 0.f;
    #pragma unroll
    for (int ct = 0; ct < 4; ++ct)
      #pragma unroll
      for (int r = 0; r < 4; ++r) { float e = acc[rt][ct][r]; s1 += e; s2 += e * e; }
    s1 += __shfl_xor(s1, 16); s2 += __shfl_xor(s2, 16);
    s1 += __shfl_xor(s1, 32); s2 += __shfl_xor(s2, 32);
    if (g == 0)
      *(float2*)(ppb + (mg * 32 + rt * 16 + c) * 32 + ng * 8) = make_float2(s1, s2);
  }
  WAITLG; BAR();                             // partials visible; all obs reads done
  {
    float mu[2], rs[2];
    #pragma unroll
    for (int rt = 0; rt < 2; ++rt) {
      int row = mg * 32 + rt * 16 + c;
      f32x4 pA = *(const f32x4*)(ppb + row * 32);
      f32x4 pB = *(const f32x4*)(ppb + row * 32 + 16);
      float S1 = pA[0] + pA[2] + pB[0] + pB[2];
      float S2 = pA[1] + pA[3] + pB[1] + pB[3];
      float m_ = S1 * (1.f / 256.f);
      float v_ = S2 * (1.f / 256.f) - m_ * m_;
      mu[rt] = m_; rs[rt] = rsqrtf(v_ + 1e-5f);
    }
    #pragma unroll
    for (int rt = 0; rt < 2; ++rt)
      #pragma unroll
      for (int ct = 0; ct < 4; ++ct) {
        f32x4 xv;
        #pragma unroll
        for (int r = 0; r < 4; ++r) xv[r] = (acc[rt][ct][r] - mu[rt]) * rs[rt];
        *(uint2*)(xb + xaddr(mg * 32 + rt * 16 + c, ng * 64 + ct * 16 + g * 4)) = pack4(xv);
      }
  }
  // Q bias preload
  f32x4 bq_r[4];
  #pragma unroll
  for (int ct = 0; ct < 4; ++ct) bq_r[ct] = *(const f32x4*)(bq + ng * 64 + ct * 16 + g * 4);
  WAITLG; BAR();                             // x visible to all waves

  // ===== Q-GEMM: K=256, 8 phases straight-line =====
  {
    const ushort_t* wsec = pw + OWq_ + wqoff;
    #pragma unroll
    for (int ct = 0; ct < 4; ++ct) { acc[0][ct] = bq_r[ct]; acc[1][ct] = bq_r[ct]; }
    #pragma unroll
    for (int ks = 0; ks < 8; ++ks) {
      bf16x8 wf[4], xf[2];
      #pragma unroll
      for (int t = 0; t < 4; ++t) wf[t] = ld_fragg(wsec + ks * 8192 + t * 512);
      #pragma unroll
      for (int rt = 0; rt < 2; ++rt)
        xf[rt] = ld_frag(xb + (((mg * 2 + rt) * 8 + ks) * 64 + lane) * 16);
      #pragma unroll
      for (int rt = 0; rt < 2; ++rt)
        #pragma unroll
        for (int ct = 0; ct < 4; ++ct) acc[rt][ct] = MFMA16(wf[ct], xf[rt], acc[rt][ct]);
    }
  }

  // park q in AGPRs; K bias preload
  unsigned qs[16];
  #pragma unroll
  for (int rt = 0; rt < 2; ++rt)
    #pragma unroll
    for (int ct = 0; ct < 4; ++ct) {
      uint2 qp = pack4(acc[rt][ct]);
      qs[(rt * 4 + ct) * 2] = to_agpr(qp.x);
      qs[(rt * 4 + ct) * 2 + 1] = to_agpr(qp.y);
    }
  f32x4 bk_r[4];
  #pragma unroll
  for (int ct = 0; ct < 4; ++ct) bk_r[ct] = *(const f32x4*)(bk + ng * 64 + ct * 16 + g * 4);

  // ===== K-GEMM: 8 phases straight-line =====
  {
    const ushort_t* wsec = pw + OWk_ + wqoff;
    #pragma unroll
    for (int ct = 0; ct < 4; ++ct) { acc[0][ct] = bk_r[ct]; acc[1][ct] = bk_r[ct]; }
    #pragma unroll
    for (int ks = 0; ks < 8; ++ks) {
      bf16x8 wf[4], xf[2];
      #pragma unroll
      for (int t = 0; t < 4; ++t) wf[t] = ld_fragg(wsec + ks * 8192 + t * 512);
      #pragma unroll
      for (int rt = 0; rt < 2; ++rt)
        xf[rt] = ld_frag(xb + (((mg * 2 + rt) * 8 + ks) * 64 + lane) * 16);
      #pragma unroll
      for (int rt = 0; rt < 2; ++rt)
        #pragma unroll
        for (int ct = 0; ct < 4; ++ct) acc[rt][ct] = MFMA16(wf[ct], xf[rt], acc[rt][ct]);
    }
  }

  // ===== S^T + softmax seam (WAVE-PRIVATE scratch -- no barrier!) =====
  uint2 p_pk[2][2];
  float bv_r[4];
  {
    f32x4 sacc[2][2];
    sacc[0][0] = splat4(0.f); sacc[0][1] = splat4(0.f);
    sacc[1][0] = splat4(0.f); sacc[1][1] = splat4(0.f);
    #pragma unroll
    for (int hf = 0; hf < 2; ++hf) {
      #pragma unroll
      for (int rt2 = 0; rt2 < 2; ++rt2)
        #pragma unroll
        for (int ctl = 0; ctl < 2; ++ctl) {
          int gr = ctl * 2 + (g >> 1);
          int off = rt2 * 1024 + (gr * 16 + c) * 16 + (g & 1) * 8;
          int qi = (rt2 * 4 + hf * 2 + ctl) * 2;
          *(uint2*)(as_ + off) = make_uint2(from_agpr(qs[qi]), from_agpr(qs[qi + 1]));
          *(uint2*)(as_ + 2048 + off) = pack4(acc[rt2][hf * 2 + ctl]);
        }
      WAITLG;
      bf16x8 qf[2], kf[2];
      #pragma unroll
      for (int t = 0; t < 2; ++t) {
        qf[t] = ld_frag(as_ + t * 1024 + lane * 16);
        kf[t] = ld_frag(as_ + 2048 + t * 1024 + lane * 16);
      }
      #pragma unroll
      for (int qt = 0; qt < 2; ++qt)
        #pragma unroll
        for (int kt = 0; kt < 2; ++kt)
          sacc[qt][kt] = MFMA16(kf[kt], qf[qt], sacc[qt][kt]);   // S^T
    }
    #pragma unroll
    for (int qt = 0; qt < 2; ++qt) {
      float sc[2][4];
      float mx = -3e38f;
      #pragma unroll
      for (int kt = 0; kt < 2; ++kt)
        #pragma unroll
        for (int r = 0; r < 4; ++r) { sc[kt][r] = sacc[qt][kt][r] * 0.125f; mx = fmaxf(mx, sc[kt][r]); }
      mx = fmaxf(mx, __shfl_xor(mx, 16));
      mx = fmaxf(mx, __shfl_xor(mx, 32));
      float sm = 0.f;
      #pragma unroll
      for (int kt = 0; kt < 2; ++kt)
        #pragma unroll
        for (int r = 0; r < 4; ++r) { float e = __expf(sc[kt][r] - mx); sc[kt][r] = e; sm += e; }
      sm += __shfl_xor(sm, 16);
      sm += __shfl_xor(sm, 32);
      float ri = 1.0f / sm;                  // fold into P: PV needs no rescale
      #pragma unroll
      for (int kt = 0; kt < 2; ++kt) {
        f32x4 pv = {sc[kt][0] * ri, sc[kt][1] * ri, sc[kt][2] * ri, sc[kt][3] * ri};
        p_pk[qt][kt] = pack4(pv);
      }
    }
    #pragma unroll
    for (int ct = 0; ct < 4; ++ct) bv_r[ct] = bv[ng * 64 + ct * 16 + c];
  }

  // ===== V-GEMM: x-as-A, 8 phases straight-line =====
  {
    const ushort_t* wsec = pw + OWv_ + wqoff;
    #pragma unroll
    for (int ct = 0; ct < 4; ++ct) {
      f32x4 b_ = splat4(bv_r[ct]);
      acc[0][ct] = b_; acc[1][ct] = b_;
    }
    #pragma unroll
    for (int ks = 0; ks < 8; ++ks) {
      bf16x8 wf[4], xf[2];
      #pragma unroll
      for (int t = 0; t < 4; ++t) wf[t] = ld_fragg(wsec + ks * 8192 + t * 512);
      #pragma unroll
      for (int rt = 0; rt < 2; ++rt)
        xf[rt] = ld_frag(xb + (((mg * 2 + rt) * 8 + ks) * 64 + lane) * 16);
      #pragma unroll
      for (int rt = 0; rt < 2; ++rt)
        #pragma unroll
        for (int ct = 0; ct < 4; ++ct) acc[rt][ct] = MFMA16(xf[rt], wf[ct], acc[rt][ct]);
    }
  }
  SCHEDB();                                  // pin V MFMAs (x reads serviced)
  BAR();                                     // all waves' V x-reads done before att writes

  // ===== PV + att store + O-init seam =====
  {
    // vT frag-linear straight from V accumulator (wave-private scratch)
    #pragma unroll
    for (int rt2 = 0; rt2 < 2; ++rt2)
      #pragma unroll
      for (int ct = 0; ct < 4; ++ct) {
        int gr = rt2 * 2 + (g >> 1);
        int off = ct * 1024 + (gr * 16 + c) * 16 + (g & 1) * 8;
        *(uint2*)(as_ + off) = pack4(acc[rt2][ct]);
      }
    // residual x re-read (wave-own region; before own att writes)
    uint2 respk[2][4];
    #pragma unroll
    for (int rt = 0; rt < 2; ++rt)
      #pragma unroll
      for (int ct = 0; ct < 4; ++ct)
        respk[rt][ct] = *(uint2*)(xb + xaddr(mg * 32 + rt * 16 + c, ng * 64 + ct * 16 + g * 4));
    WAITLG;
    bf16x8 vf[4];
    #pragma unroll
    for (int dt = 0; dt < 4; ++dt) vf[dt] = ld_frag(as_ + dt * 1024 + lane * 16);
    const int l1 = (g & 1) * 32 + c, l2 = l1 + 16;
    const bool hi = (g >= 2);
    #pragma unroll
    for (int qt = 0; qt < 2; ++qt) {
      unsigned x0k0 = __shfl(p_pk[qt][0].x, l1), x0k1 = __shfl(p_pk[qt][1].x, l1);
      unsigned y0k0 = __shfl(p_pk[qt][0].y, l1), y0k1 = __shfl(p_pk[qt][1].y, l1);
      unsigned x1k0 = __shfl(p_pk[qt][0].x, l2), x1k1 = __shfl(p_pk[qt][1].x, l2);
      unsigned y1k0 = __shfl(p_pk[qt][0].y, l2), y1k1 = __shfl(p_pk[qt][1].y, l2);
      bf16x8 pf = u4b(hi ? x0k1 : x0k0, hi ? y0k1 : y0k0, hi ? x1k1 : x1k0, hi ? y1k1 : y1k0);
      #pragma unroll
      for (int dt = 0; dt < 4; ++dt) {
        f32x4 o = splat4(0.f);
        o = MFMA16(vf[dt], pf, o);           // P pre-scaled
        *(uint2*)(xb + xaddr(mg * 32 + qt * 16 + c, ng * 64 + dt * 16 + g * 4)) = pack4(o);
      }
    }
    // O bias after PV; O-GEMM C-init
    f32x4 bo_r[4];
    #pragma unroll
    for (int ct = 0; ct < 4; ++ct) bo_r[ct] = *(const f32x4*)(bo + ng * 64 + ct * 16 + g * 4);
    #pragma unroll
    for (int ct = 0; ct < 4; ++ct) {
      #pragma unroll
      for (int rt = 0; rt < 2; ++rt) acc[rt][ct] = bo_r[ct] + unpk(respk[rt][ct]);
    }
  }
  WAITLG; BAR();                             // att visible to all waves

  // ===== O-GEMM: 8 phases straight-line =====
  {
    const ushort_t* wsec = pw + OWo_ + wqoff;
    #pragma unroll
    for (int ks = 0; ks < 8; ++ks) {
      bf16x8 wf[4], xf[2];
      #pragma unroll
      for (int t = 0; t < 4; ++t) wf[t] = ld_fragg(wsec + ks * 8192 + t * 512);
      #pragma unroll
      for (int rt = 0; rt < 2; ++rt)
        xf[rt] = ld_frag(xb + (((mg * 2 + rt) * 8 + ks) * 64 + lane) * 16);
      #pragma unroll
      for (int rt = 0; rt < 2; ++rt)
        #pragma unroll
        for (int ct = 0; ct < 4; ++ct) acc[rt][ct] = MFMA16(wf[ct], xf[rt], acc[rt][ct]);
    }
  }

  // ---- LN2 + pool ----
  #pragma unroll
  for (int rt = 0; rt < 2; ++rt) {
    float s1 = 0.f, s2 = 0.f;
    #pragma unroll
    for (int ct = 0; ct < 4; ++ct)
      #pragma unroll
      for (int r = 0; r < 4; ++r) { float e = acc[rt][ct][r]; s1 += e; s2 += e * e; }
    s1 += __shfl_xor(s1, 16); s2 += __shfl_xor(s2, 16);
    s1 += __shfl_xor(s1, 32); s2 += __shfl_xor(s2, 32);
    if (g == 0)
      *(float2*)(ppb + (mg * 32 + rt * 16 + c) * 32 + ng * 8) = make_float2(s1, s2);
  }
  WAITLG; BAR();
  {
    float mu[2], rs[2];
    #pragma unroll
    for (int rt = 0; rt < 2; ++rt) {
      int row = mg * 32 + rt * 16 + c;
      f32x4 pA = *(const f32x4*)(ppb + row * 32);
      f32x4 pB = *(const f32x4*)(ppb + row * 32 + 16);
      float S1 = pA[0] + pA[2] + pB[0] + pB[2];
      float S2 = pA[1] + pA[3] + pB[1] + pB[3];
      float m_ = S1 * (1.f / 256.f);
      float v_ = S2 * (1.f / 256.f) - m_ * m_;
      mu[rt] = m_; rs[rt] = rsqrtf(v_ + 1e-5f);
    }
    f32x4 ps[4];
    #pragma unroll
    for (int ct = 0; ct < 4; ++ct) {
      #pragma unroll
      for (int r = 0; r < 4; ++r)
        ps[ct][r] = (acc[0][ct][r] - mu[0]) * rs[0] + (acc[1][ct][r] - mu[1]) * rs[1];
    }
    #pragma unroll
    for (int st = 1; st < 16; st <<= 1)
      #pragma unroll
      for (int ct = 0; ct < 4; ++ct)
        #pragma unroll
        for (int r = 0; r < 4; ++r) ps[ct][r] += __shfl_xor(ps[ct][r], st);
    if (c == 0) {
      #pragma unroll
      for (int ct = 0; ct < 4; ++ct) {
        f32x4 pv;
        #pragma unroll
        for (int r = 0; r < 4; ++r) pv[r] = ps[ct][r] * (1.f / 32.f);
        *(uint2*)(poolb + mg * 528 + (ng * 64 + ct * 16 + g * 4) * 2) = pack4(pv);
      }
    }
  }
  // zero pool/y1 rows 2..15 (cols 0..255)
  #pragma unroll
  for (int it = 0; it < 4; ++it) {
    int idx = it * 512 + tid;
    if (idx < 1792) {
      int row = 2 + (idx >> 7), col = idx & 127;
      *(unsigned*)(poolb + row * 528 + col * 4) = 0;
      *(unsigned*)(y1b + row * 528 + col * 4) = 0;
    }
  }
  WAITLG; BAR();

  // ===== tail MLP: M=16 MFMA (2 valid rows); wave wv owns cols wv*32..+31 =====
  f32x4 t1[2];
  #pragma unroll
  for (int ctl = 0; ctl < 2; ++ctl) t1[ctl] = splat4(b1[wv * 32 + ctl * 16 + c]);
  #pragma unroll
  for (int ks = 0; ks < 8; ++ks) {
    bf16x8 a = ld_frag(poolb + c * 528 + ks * 64 + g * 16);
    #pragma unroll
    for (int ctl = 0; ctl < 2; ++ctl) {
      bf16x8 b = *(const bf16x8*)(pw + OW1_ + (size_t)(((wv * 2 + ctl) * 8 + ks) * 64 + lane) * 8);
      t1[ctl] = MFMA16(a, b, t1[ctl]);
    }
  }
  if (g == 0) {
    #pragma unroll
    for (int ctl = 0; ctl < 2; ++ctl)
      #pragma unroll
      for (int r = 0; r < 4; ++r)
        *(__bf16*)(y1b + r * 528 + (wv * 32 + ctl * 16 + c) * 2) = (__bf16)silu_f(t1[ctl][r]);
  }
  WAITLG; BAR();
  f32x4 t2[2];
  #pragma unroll
  for (int ctl = 0; ctl < 2; ++ctl) t2[ctl] = splat4(b2[wv * 32 + ctl * 16 + c]);
  #pragma unroll
  for (int ks = 0; ks < 8; ++ks) {
    bf16x8 a = ld_frag(y1b + c * 528 + ks * 64 + g * 16);
    #pragma unroll
    for (int ctl = 0; ctl < 2; ++ctl) {
      bf16x8 b = *(const bf16x8*)(pw + OW2_ + (size_t)(((wv * 2 + ctl) * 8 + ks) * 64 + lane) * 8);
      t2[ctl] = MFMA16(a, b, t2[ctl]);
    }
  }
  if (g == 0) {
    float part[4] = {0.f, 0.f, 0.f, 0.f};
    #pragma unroll
    for (int ctl = 0; ctl < 2; ++ctl) {
      float wvv = Wval[wv * 32 + ctl * 16 + c];
      #pragma unroll
      for (int r = 0; r < 4; ++r) part[r] += silu_f(t2[ctl][r]) * wvv;
    }
    #pragma unroll
    for (int m = 1; m < 16; m <<= 1) {
      #pragma unroll
      for (int r = 0; r < 4; ++r) part[r] += __shfl_xor(part[r], m);
    }
    if (c == 0) {
      float4 p4 = make_float4(part[0], part[1], part[2], part[3]);
      *(float4*)(ptlb + wv * 16) = p4;
    }
  }
  WAITLG; BAR();
  if (tid < 2) {
    float s = Wval[256] + bval[0];
    const float* pt = (const float*)ptlb;
    #pragma unroll
    for (int w8 = 0; w8 < 8; ++w8) s += pt[w8 * 4 + tid];
    out[(size_t)blockIdx.x * 2 + tid] = s;
  }
}

extern "C" void kernel_launch(void* const* d_in, const int* in_sizes, int n_in,
                              void* d_out, int out_size, void* d_ws, size_t ws_size,
                              hipStream_t stream) {
  (void)in_sizes; (void)n_in; (void)out_size; (void)ws_size;
  const float* obs  = (const float*)d_in[0];
  const float* Wemb = (const float*)d_in[1];
  const float* bemb = (const float*)d_in[2];
  const float* Wq   = (const float*)d_in[3];
  const float* bq   = (const float*)d_in[4];
  const float* Wk   = (const float*)d_in[5];
  const float* bk   = (const float*)d_in[6];
  const float* Wv   = (const float*)d_in[7];
  const float* bv   = (const float*)d_in[8];
  const float* Wo   = (const float*)d_in[9];
  const float* bo   = (const float*)d_in[10];
  const float* W1   = (const float*)d_in[11];
  const float* b1   = (const float*)d_in[12];
  const float* W2   = (const float*)d_in[13];
  const float* b2   = (const float*)d_in[14];
  const float* Wval = (const float*)d_in[15];
  const float* bval = (const float*)d_in[16];
  ushort_t* ws = (ushort_t*)d_ws;
  float* out = (float*)d_out;

  pack_weights<<<208, 256, 0, stream>>>(Wemb, Wq, Wk, Wv, Wo, W1, W2, ws);
  poca_fused<<<4096, 512, 0, stream>>>(obs, ws, bemb, bq, bk, bv, bo, b1, b2, Wval, bval, out);
}

// Round 17
// 288.026 us; speedup vs baseline: 1.1013x; 1.0252x over previous
//
#include <hip/hip_runtime.h>

// POCACritic fused forward: B=8192, N=32, OBS=128, H=256, HEADS=4 (HD=64)
// R17 = R16 (295us best) + P-through-LDS: softmax stores P directly in the
// PV B-fragment layout ([m_q][m_k] row-major, 64B rows; store addr
// c*64+kt*32+g*8 from C-layout, read addr c*64+g*16 = exact B-frag), so
// p_pk never crosses V-GEMM in registers (kills the last ~8-dword spill)
// and PV's 16 shuffles become 2 ds_read_b128. Scratch 6KB/wave
// (4KB S-staging/vT + 2KB P); LDS = 32K x + 48K scratch = 80KB exactly.

typedef __bf16 bf16x8 __attribute__((ext_vector_type(8)));
typedef float f32x4 __attribute__((ext_vector_type(4)));
typedef unsigned short ushort_t;

#define DEVI static __device__ __forceinline__
#define MFMA16(a, b, cc) __builtin_amdgcn_mfma_f32_16x16x32_bf16((a), (b), (cc), 0, 0, 0)

#define WAITLG asm volatile("s_waitcnt lgkmcnt(0)" ::: "memory")
#define BAR() __builtin_amdgcn_s_barrier()
#define SCHEDB() __builtin_amdgcn_sched_barrier(0)

// packed-weight offsets (ushort elems). [Kks][16ct][64l][8]: ks-stride 8192,
// ct-stride 512 (ushorts).
constexpr int OWemb_ = 0;               // 4 ks (K=128)
constexpr int OWq_   = 32768;           // 8 ks each (K=256)
constexpr int OWk_   = OWq_ + 65536;
constexpr int OWv_   = OWk_ + 65536;
constexpr int OWo_   = OWv_ + 65536;
constexpr int OW1_   = OWo_ + 65536;    // tail layout [ct16][ks8][lane][8]
constexpr int OW2_   = OW1_ + 65536;

// LDS layout (bytes)
constexpr int OBS_STRIDE = 264;
constexpr int L_SCR = 32768;              // x/att frag-linear 32KB at 0
constexpr int SCR_W = 6144;               // per-wave: 0-4K S-staging/vT, 4-6K P
constexpr int LDS_TOTAL = 32768 + 8 * SCR_W;  // 81920 exactly
static_assert(LDS_TOTAL <= 81920, "need <=80KB for 2 blocks/CU");

DEVI float silu_f(float x) { return x / (1.0f + __expf(-x)); }
DEVI f32x4 splat4(float x) { f32x4 v = {x, x, x, x}; return v; }
DEVI uint2 pack4(f32x4 v) {
  union { __bf16 h[4]; uint2 u; } x;
  x.h[0] = (__bf16)v[0]; x.h[1] = (__bf16)v[1];
  x.h[2] = (__bf16)v[2]; x.h[3] = (__bf16)v[3];
  return x.u;
}
DEVI f32x4 unpk(uint2 u) {
  union { uint2 u2; __bf16 h[4]; } x; x.u2 = u;
  f32x4 v = {(float)x.h[0], (float)x.h[1], (float)x.h[2], (float)x.h[3]};
  return v;
}
DEVI bf16x8 ld_frag(const char* p) { return *(const bf16x8*)p; }
DEVI bf16x8 ld_fragg(const ushort_t* p) { return *(const bf16x8*)p; }
// explicit AGPR parking (keeps arch-VGPR pressure under the 64-reg cap)
DEVI unsigned to_agpr(unsigned v) {
  unsigned d;
  asm volatile("v_accvgpr_write_b32 %0, %1" : "=a"(d) : "v"(v));
  return d;
}
DEVI unsigned from_agpr(unsigned a) {
  unsigned d;
  asm volatile("v_accvgpr_read_b32 %0, %1" : "=v"(d) : "a"(a));
  return d;
}
// frag-linear byte offset for 4-elem group at (row, k4); k4 % 4 == 0
DEVI int xaddr(int row, int k4) {
  int t = row >> 4, cc = row & 15;
  int ks = k4 >> 5, kg = (k4 >> 3) & 3, half = (k4 >> 2) & 1;
  return ((t * 8 + ks) * 64 + kg * 16 + cc) * 16 + half * 8;
}

// ---- weight pre-pack (identical layouts to R16) ----
__global__ void pack_weights(const float* __restrict__ Wemb, const float* __restrict__ Wq,
                             const float* __restrict__ Wk, const float* __restrict__ Wv,
                             const float* __restrict__ Wo, const float* __restrict__ W1,
                             const float* __restrict__ W2, ushort_t* __restrict__ ws) {
  int t = blockIdx.x * 256 + threadIdx.x;
  if (t >= 53248) return;
  const float* src;
  int dst, n, k0;
  if (t < 4096) {                 // emb: [4ks][16ct][64l][8]
    int rem = t & 1023;
    int ctg = rem >> 6, l = rem & 63;
    n = ctg * 16 + (l & 15);
    k0 = (t >> 10) * 32 + (l >> 4) * 8;
    src = Wemb; dst = OWemb_ + t * 8;
  } else if (t < 36864) {         // q,k,v,o: [8ks][16ct][64l][8]
    int u = t - 4096, m = u >> 13, loc = u & 8191;
    int rem = loc & 1023;
    int ctg = rem >> 6, l = rem & 63;
    n = ctg * 16 + (l & 15);
    k0 = (loc >> 10) * 32 + (l >> 4) * 8;
    src = (m == 0) ? Wq : (m == 1) ? Wk : (m == 2) ? Wv : Wo;
    dst = OWq_ + m * 65536 + loc * 8;
  } else {                        // W1,W2 (tail): [ct16][ks8][lane][8]
    int u = t - 36864, m = u >> 13, loc = u & 8191;
    int ln = loc & 63, ks = (loc >> 6) & 7, ct = loc >> 9;
    n = ct * 16 + (ln & 15);
    k0 = ks * 32 + (ln >> 4) * 8;
    src = m ? W2 : W1; dst = OW1_ + m * 65536 + loc * 8;
  }
  union { __bf16 h[8]; uint4 u; } pk;
  #pragma unroll
  for (int j = 0; j < 8; ++j) pk.h[j] = (__bf16)src[(k0 + j) * 256 + n];
  *(uint4*)(ws + dst) = pk.u;
}

__global__ __launch_bounds__(512, 4)
void poca_fused(const float* __restrict__ obs, const ushort_t* __restrict__ pw,
                const float* __restrict__ b_emb, const float* __restrict__ bq,
                const float* __restrict__ bk, const float* __restrict__ bv,
                const float* __restrict__ bo, const float* __restrict__ b1,
                const float* __restrict__ b2, const float* __restrict__ Wval,
                const float* __restrict__ bval, float* __restrict__ out) {
  __shared__ __align__(128) char lds[LDS_TOTAL];
  const int tid = threadIdx.x;
  const int wv = tid >> 6, lane = tid & 63;
  const int g = lane >> 4, c = lane & 15;
  const int mg = wv >> 2, ng = wv & 3;       // wave = (batch mg, head/ncols ng)
  char* xb = lds;                            // obs (row-major 264) -> x -> att (frag-linear)
  char* scr = lds + L_SCR;
  char* as_ = scr + wv * SCR_W;              // wave-private: 0-4K stage/vT, 4-6K P
  char* ppb = scr;                           // LN partials overlay (scratch dead at LN1/LN2)
  char* poolb = scr;                         // tail overlays scratch (dead)
  char* y1b = scr + 8448;
  char* ptlb = scr + 16896;

  // per-wave weight fragment base (this wave's ng quarter)
  const size_t wqoff = (size_t)((ng * 4) * 64 + lane) * 8;

  // emb bias preload
  f32x4 bemb_r[4];
  #pragma unroll
  for (int ct = 0; ct < 4; ++ct) bemb_r[ct] = *(const f32x4*)(b_emb + ng * 64 + ct * 16 + g * 4);

  // ---- stage obs: 64 rows x 128 f32 -> bf16 row-major stride 264 ----
  {
    const float4* op = (const float4*)(obs + (size_t)blockIdx.x * 64 * 128);
    #pragma unroll
    for (int it = 0; it < 4; ++it) {
      int idx = it * 512 + tid;              // 0..2047
      float4 v = op[idx];
      int row = idx >> 5, col4 = idx & 31;
      union { __bf16 h[4]; uint2 u; } cv;
      cv.h[0] = (__bf16)v.x; cv.h[1] = (__bf16)v.y;
      cv.h[2] = (__bf16)v.z; cv.h[3] = (__bf16)v.w;
      *(uint2*)(xb + row * OBS_STRIDE + col4 * 8) = cv.u;
    }
  }
  WAITLG; BAR();                             // obs visible to all waves

  f32x4 acc[2][4];

  // ===== emb: ent = silu(obs @ Wemb + b_emb), K=128, straight-line =====
  {
    const ushort_t* wsec = pw + OWemb_ + wqoff;
    #pragma unroll
    for (int ct = 0; ct < 4; ++ct) { acc[0][ct] = bemb_r[ct]; acc[1][ct] = bemb_r[ct]; }
    #pragma unroll
    for (int p = 0; p < 4; ++p) {
      bf16x8 wf[4], xf[2];
      #pragma unroll
      for (int t = 0; t < 4; ++t) wf[t] = ld_fragg(wsec + p * 8192 + t * 512);
      #pragma unroll
      for (int rt = 0; rt < 2; ++rt)
        xf[rt] = ld_frag(xb + ((mg * 2 + rt) * 16 + c) * OBS_STRIDE + p * 64 + g * 16);
      #pragma unroll
      for (int rt = 0; rt < 2; ++rt)
        #pragma unroll
        for (int ct = 0; ct < 4; ++ct) acc[rt][ct] = MFMA16(wf[ct], xf[rt], acc[rt][ct]);
    }
  }
  SCHEDB();                                  // pin emb MFMAs (obs reads serviced)

  // ---- silu + LN1 -> x frag-linear ----
  #pragma unroll
  for (int rt = 0; rt < 2; ++rt)
    #pragma unroll
    for (int ct = 0; ct < 4; ++ct)
      #pragma unroll
      for (int r = 0; r < 4; ++r) acc[rt][ct][r] = silu_f(acc[rt][ct][r]);
  #pragma unroll
  for (int rt = 0; rt < 2; ++rt) {
    float s1 = 0.f, s2 = 0.f;
    #pragma unroll
    for (int ct = 0; ct < 4; ++ct)
      #pragma unroll
      for (int r = 0; r < 4; ++r) { float e = acc[rt][ct][r]; s1 += e; s2 += e * e; }
    s1 += __shfl_xor(s1, 16); s2 += __shfl_xor(s2, 16);
    s1 += __shfl_xor(s1, 32); s2 += __shfl_xor(s2, 32);
    if (g == 0)
      *(float2*)(ppb + (mg * 32 + rt * 16 + c) * 32 + ng * 8) = make_float2(s1, s2);
  }
  WAITLG; BAR();                             // partials visible; all obs reads done
  {
    float mu[2], rs[2];
    #pragma unroll
    for (int rt = 0; rt < 2; ++rt) {
      int row = mg * 32 + rt * 16 + c;
      f32x4 pA = *(const f32x4*)(ppb + row * 32);
      f32x4 pB = *(const f32x4*)(ppb + row * 32 + 16);
      float S1 = pA[0] + pA[2] + pB[0] + pB[2];
      float S2 = pA[1] + pA[3] + pB[1] + pB[3];
      float m_ = S1 * (1.f / 256.f);
      float v_ = S2 * (1.f / 256.f) - m_ * m_;
      mu[rt] = m_; rs[rt] = rsqrtf(v_ + 1e-5f);
    }
    #pragma unroll
    for (int rt = 0; rt < 2; ++rt)
      #pragma unroll
      for (int ct = 0; ct < 4; ++ct) {
        f32x4 xv;
        #pragma unroll
        for (int r = 0; r < 4; ++r) xv[r] = (acc[rt][ct][r] - mu[rt]) * rs[rt];
        *(uint2*)(xb + xaddr(mg * 32 + rt * 16 + c, ng * 64 + ct * 16 + g * 4)) = pack4(xv);
      }
  }
  // Q bias preload
  f32x4 bq_r[4];
  #pragma unroll
  for (int ct = 0; ct < 4; ++ct) bq_r[ct] = *(const f32x4*)(bq + ng * 64 + ct * 16 + g * 4);
  WAITLG; BAR();                             // x visible to all waves

  // ===== Q-GEMM: K=256, straight-line =====
  {
    const ushort_t* wsec = pw + OWq_ + wqoff;
    #pragma unroll
    for (int ct = 0; ct < 4; ++ct) { acc[0][ct] = bq_r[ct]; acc[1][ct] = bq_r[ct]; }
    #pragma unroll
    for (int ks = 0; ks < 8; ++ks) {
      bf16x8 wf[4], xf[2];
      #pragma unroll
      for (int t = 0; t < 4; ++t) wf[t] = ld_fragg(wsec + ks * 8192 + t * 512);
      #pragma unroll
      for (int rt = 0; rt < 2; ++rt)
        xf[rt] = ld_frag(xb + (((mg * 2 + rt) * 8 + ks) * 64 + lane) * 16);
      #pragma unroll
      for (int rt = 0; rt < 2; ++rt)
        #pragma unroll
        for (int ct = 0; ct < 4; ++ct) acc[rt][ct] = MFMA16(wf[ct], xf[rt], acc[rt][ct]);
    }
  }

  // park q in AGPRs; K bias preload
  unsigned qs[16];
  #pragma unroll
  for (int rt = 0; rt < 2; ++rt)
    #pragma unroll
    for (int ct = 0; ct < 4; ++ct) {
      uint2 qp = pack4(acc[rt][ct]);
      qs[(rt * 4 + ct) * 2] = to_agpr(qp.x);
      qs[(rt * 4 + ct) * 2 + 1] = to_agpr(qp.y);
    }
  f32x4 bk_r[4];
  #pragma unroll
  for (int ct = 0; ct < 4; ++ct) bk_r[ct] = *(const f32x4*)(bk + ng * 64 + ct * 16 + g * 4);

  // ===== K-GEMM: straight-line =====
  {
    const ushort_t* wsec = pw + OWk_ + wqoff;
    #pragma unroll
    for (int ct = 0; ct < 4; ++ct) { acc[0][ct] = bk_r[ct]; acc[1][ct] = bk_r[ct]; }
    #pragma unroll
    for (int ks = 0; ks < 8; ++ks) {
      bf16x8 wf[4], xf[2];
      #pragma unroll
      for (int t = 0; t < 4; ++t) wf[t] = ld_fragg(wsec + ks * 8192 + t * 512);
      #pragma unroll
      for (int rt = 0; rt < 2; ++rt)
        xf[rt] = ld_frag(xb + (((mg * 2 + rt) * 8 + ks) * 64 + lane) * 16);
      #pragma unroll
      for (int rt = 0; rt < 2; ++rt)
        #pragma unroll
        for (int ct = 0; ct < 4; ++ct) acc[rt][ct] = MFMA16(wf[ct], xf[rt], acc[rt][ct]);
    }
  }

  // ===== S^T + softmax seam (wave-private; P stored to LDS in B-frag layout) =====
  float bv_r[4];
  {
    f32x4 sacc[2][2];
    sacc[0][0] = splat4(0.f); sacc[0][1] = splat4(0.f);
    sacc[1][0] = splat4(0.f); sacc[1][1] = splat4(0.f);
    #pragma unroll
    for (int hf = 0; hf < 2; ++hf) {
      #pragma unroll
      for (int rt2 = 0; rt2 < 2; ++rt2)
        #pragma unroll
        for (int ctl = 0; ctl < 2; ++ctl) {
          int gr = ctl * 2 + (g >> 1);
          int off = rt2 * 1024 + (gr * 16 + c) * 16 + (g & 1) * 8;
          int qi = (rt2 * 4 + hf * 2 + ctl) * 2;
          *(uint2*)(as_ + off) = make_uint2(from_agpr(qs[qi]), from_agpr(qs[qi + 1]));
          *(uint2*)(as_ + 2048 + off) = pack4(acc[rt2][hf * 2 + ctl]);
        }
      WAITLG;
      bf16x8 qf[2], kf[2];
      #pragma unroll
      for (int t = 0; t < 2; ++t) {
        qf[t] = ld_frag(as_ + t * 1024 + lane * 16);
        kf[t] = ld_frag(as_ + 2048 + t * 1024 + lane * 16);
      }
      #pragma unroll
      for (int qt = 0; qt < 2; ++qt)
        #pragma unroll
        for (int kt = 0; kt < 2; ++kt)
          sacc[qt][kt] = MFMA16(kf[kt], qf[qt], sacc[qt][kt]);   // S^T
    }
    #pragma unroll
    for (int qt = 0; qt < 2; ++qt) {
      float sc[2][4];
      float mx = -3e38f;
      #pragma unroll
      for (int kt = 0; kt < 2; ++kt)
        #pragma unroll
        for (int r = 0; r < 4; ++r) { sc[kt][r] = sacc[qt][kt][r] * 0.125f; mx = fmaxf(mx, sc[kt][r]); }
      mx = fmaxf(mx, __shfl_xor(mx, 16));
      mx = fmaxf(mx, __shfl_xor(mx, 32));
      float sm = 0.f;
      #pragma unroll
      for (int kt = 0; kt < 2; ++kt)
        #pragma unroll
        for (int r = 0; r < 4; ++r) { float e = __expf(sc[kt][r] - mx); sc[kt][r] = e; sm += e; }
      sm += __shfl_xor(sm, 16);
      sm += __shfl_xor(sm, 32);
      float ri = 1.0f / sm;                  // fold into P: PV needs no rescale
      // P store: [m_q=c][m_k] row-major (64B rows). C-layout lane holds
      // (m_q=c, m_k=kt*16+g*4+r) -> uint2 at c*64 + kt*32 + g*8.
      #pragma unroll
      for (int kt = 0; kt < 2; ++kt) {
        f32x4 pv = {sc[kt][0] * ri, sc[kt][1] * ri, sc[kt][2] * ri, sc[kt][3] * ri};
        *(uint2*)(as_ + 4096 + qt * 1024 + c * 64 + kt * 32 + g * 8) = pack4(pv);
      }
    }
    #pragma unroll
    for (int ct = 0; ct < 4; ++ct) bv_r[ct] = bv[ng * 64 + ct * 16 + c];
  }

  // ===== V-GEMM: x-as-A, straight-line (nothing but acc crosses) =====
  {
    const ushort_t* wsec = pw + OWv_ + wqoff;
    #pragma unroll
    for (int ct = 0; ct < 4; ++ct) {
      f32x4 b_ = splat4(bv_r[ct]);
      acc[0][ct] = b_; acc[1][ct] = b_;
    }
    #pragma unroll
    for (int ks = 0; ks < 8; ++ks) {
      bf16x8 wf[4], xf[2];
      #pragma unroll
      for (int t = 0; t < 4; ++t) wf[t] = ld_fragg(wsec + ks * 8192 + t * 512);
      #pragma unroll
      for (int rt = 0; rt < 2; ++rt)
        xf[rt] = ld_frag(xb + (((mg * 2 + rt) * 8 + ks) * 64 + lane) * 16);
      #pragma unroll
      for (int rt = 0; rt < 2; ++rt)
        #pragma unroll
        for (int ct = 0; ct < 4; ++ct) acc[rt][ct] = MFMA16(xf[rt], wf[ct], acc[rt][ct]);
    }
  }
  SCHEDB();                                  // pin V MFMAs (x reads serviced)
  BAR();                                     // all waves' V x-reads done before att writes

  // ===== PV + att store + O-init seam =====
  {
    // vT frag-linear straight from V accumulator (wave-private scratch 0-4K)
    #pragma unroll
    for (int rt2 = 0; rt2 < 2; ++rt2)
      #pragma unroll
      for (int ct = 0; ct < 4; ++ct) {
        int gr = rt2 * 2 + (g >> 1);
        int off = ct * 1024 + (gr * 16 + c) * 16 + (g & 1) * 8;
        *(uint2*)(as_ + off) = pack4(acc[rt2][ct]);
      }
    // residual x re-read (wave-own region; before own att writes)
    uint2 respk[2][4];
    #pragma unroll
    for (int rt = 0; rt < 2; ++rt)
      #pragma unroll
      for (int ct = 0; ct < 4; ++ct)
        respk[rt][ct] = *(uint2*)(xb + xaddr(mg * 32 + rt * 16 + c, ng * 64 + ct * 16 + g * 4));
    WAITLG;
    bf16x8 vf[4];
    #pragma unroll
    for (int dt = 0; dt < 4; ++dt) vf[dt] = ld_frag(as_ + dt * 1024 + lane * 16);
    #pragma unroll
    for (int qt = 0; qt < 2; ++qt) {
      // P B-frag read: lane l -> [m_q=l&15][m_k=(l>>4)*8+j] = c*64 + g*16
      bf16x8 pf = ld_frag(as_ + 4096 + qt * 1024 + c * 64 + g * 16);
      #pragma unroll
      for (int dt = 0; dt < 4; ++dt) {
        f32x4 o = splat4(0.f);
        o = MFMA16(vf[dt], pf, o);           // P pre-scaled
        *(uint2*)(xb + xaddr(mg * 32 + qt * 16 + c, ng * 64 + dt * 16 + g * 4)) = pack4(o);
      }
    }
    // O bias after PV; O-GEMM C-init
    f32x4 bo_r[4];
    #pragma unroll
    for (int ct = 0; ct < 4; ++ct) bo_r[ct] = *(const f32x4*)(bo + ng * 64 + ct * 16 + g * 4);
    #pragma unroll
    for (int ct = 0; ct < 4; ++ct) {
      #pragma unroll
      for (int rt = 0; rt < 2; ++rt) acc[rt][ct] = bo_r[ct] + unpk(respk[rt][ct]);
    }
  }
  WAITLG; BAR();                             // att visible to all waves

  // ===== O-GEMM: straight-line =====
  {
    const ushort_t* wsec = pw + OWo_ + wqoff;
    #pragma unroll
    for (int ks = 0; ks < 8; ++ks) {
      bf16x8 wf[4], xf[2];
      #pragma unroll
      for (int t = 0; t < 4; ++t) wf[t] = ld_fragg(wsec + ks * 8192 + t * 512);
      #pragma unroll
      for (int rt = 0; rt < 2; ++rt)
        xf[rt] = ld_frag(xb + (((mg * 2 + rt) * 8 + ks) * 64 + lane) * 16);
      #pragma unroll
      for (int rt = 0; rt < 2; ++rt)
        #pragma unroll
        for (int ct = 0; ct < 4; ++ct) acc[rt][ct] = MFMA16(wf[ct], xf[rt], acc[rt][ct]);
    }
  }

  // ---- LN2 + pool ----
  #pragma unroll
  for (int rt = 0; rt < 2; ++rt) {
    float s1 = 0.f, s2 = 0.f;
    #pragma unroll
    for (int ct = 0; ct < 4; ++ct)
      #pragma unroll
      for (int r = 0; r < 4; ++r) { float e = acc[rt][ct][r]; s1 += e; s2 += e * e; }
    s1 += __shfl_xor(s1, 16); s2 += __shfl_xor(s2, 16);
    s1 += __shfl_xor(s1, 32); s2 += __shfl_xor(s2, 32);
    if (g == 0)
      *(float2*)(ppb + (mg * 32 + rt * 16 + c) * 32 + ng * 8) = make_float2(s1, s2);
  }
  WAITLG; BAR();
  {
    float mu[2], rs[2];
    #pragma unroll
    for (int rt = 0; rt < 2; ++rt) {
      int row = mg * 32 + rt * 16 + c;
      f32x4 pA = *(const f32x4*)(ppb + row * 32);
      f32x4 pB = *(const f32x4*)(ppb + row * 32 + 16);
      float S1 = pA[0] + pA[2] + pB[0] + pB[2];
      float S2 = pA[1] + pA[3] + pB[1] + pB[3];
      float m_ = S1 * (1.f / 256.f);
      float v_ = S2 * (1.f / 256.f) - m_ * m_;
      mu[rt] = m_; rs[rt] = rsqrtf(v_ + 1e-5f);
    }
    f32x4 ps[4];
    #pragma unroll
    for (int ct = 0; ct < 4; ++ct) {
      #pragma unroll
      for (int r = 0; r < 4; ++r)
        ps[ct][r] = (acc[0][ct][r] - mu[0]) * rs[0] + (acc[1][ct][r] - mu[1]) * rs[1];
    }
    #pragma unroll
    for (int st = 1; st < 16; st <<= 1)
      #pragma unroll
      for (int ct = 0; ct < 4; ++ct)
        #pragma unroll
        for (int r = 0; r < 4; ++r) ps[ct][r] += __shfl_xor(ps[ct][r], st);
    if (c == 0) {
      #pragma unroll
      for (int ct = 0; ct < 4; ++ct) {
        f32x4 pv;
        #pragma unroll
        for (int r = 0; r < 4; ++r) pv[r] = ps[ct][r] * (1.f / 32.f);
        *(uint2*)(poolb + mg * 528 + (ng * 64 + ct * 16 + g * 4) * 2) = pack4(pv);
      }
    }
  }
  // zero pool/y1 rows 2..15 (cols 0..255)
  #pragma unroll
  for (int it = 0; it < 4; ++it) {
    int idx = it * 512 + tid;
    if (idx < 1792) {
      int row = 2 + (idx >> 7), col = idx & 127;
      *(unsigned*)(poolb + row * 528 + col * 4) = 0;
      *(unsigned*)(y1b + row * 528 + col * 4) = 0;
    }
  }
  WAITLG; BAR();

  // ===== tail MLP: M=16 MFMA (2 valid rows); wave wv owns cols wv*32..+31 =====
  f32x4 t1[2];
  #pragma unroll
  for (int ctl = 0; ctl < 2; ++ctl) t1[ctl] = splat4(b1[wv * 32 + ctl * 16 + c]);
  #pragma unroll
  for (int ks = 0; ks < 8; ++ks) {
    bf16x8 a = ld_frag(poolb + c * 528 + ks * 64 + g * 16);
    #pragma unroll
    for (int ctl = 0; ctl < 2; ++ctl) {
      bf16x8 b = *(const bf16x8*)(pw + OW1_ + (size_t)(((wv * 2 + ctl) * 8 + ks) * 64 + lane) * 8);
      t1[ctl] = MFMA16(a, b, t1[ctl]);
    }
  }
  if (g == 0) {
    #pragma unroll
    for (int ctl = 0; ctl < 2; ++ctl)
      #pragma unroll
      for (int r = 0; r < 4; ++r)
        *(__bf16*)(y1b + r * 528 + (wv * 32 + ctl * 16 + c) * 2) = (__bf16)silu_f(t1[ctl][r]);
  }
  WAITLG; BAR();
  f32x4 t2[2];
  #pragma unroll
  for (int ctl = 0; ctl < 2; ++ctl) t2[ctl] = splat4(b2[wv * 32 + ctl * 16 + c]);
  #pragma unroll
  for (int ks = 0; ks < 8; ++ks) {
    bf16x8 a = ld_frag(y1b + c * 528 + ks * 64 + g * 16);
    #pragma unroll
    for (int ctl = 0; ctl < 2; ++ctl) {
      bf16x8 b = *(const bf16x8*)(pw + OW2_ + (size_t)(((wv * 2 + ctl) * 8 + ks) * 64 + lane) * 8);
      t2[ctl] = MFMA16(a, b, t2[ctl]);
    }
  }
  if (g == 0) {
    float part[4] = {0.f, 0.f, 0.f, 0.f};
    #pragma unroll
    for (int ctl = 0; ctl < 2; ++ctl) {
      float wvv = Wval[wv * 32 + ctl * 16 + c];
      #pragma unroll
      for (int r = 0; r < 4; ++r) part[r] += silu_f(t2[ctl][r]) * wvv;
    }
    #pragma unroll
    for (int m = 1; m < 16; m <<= 1) {
      #pragma unroll
      for (int r = 0; r < 4; ++r) part[r] += __shfl_xor(part[r], m);
    }
    if (c == 0) {
      float4 p4 = make_float4(part[0], part[1], part[2], part[3]);
      *(float4*)(ptlb + wv * 16) = p4;
    }
  }
  WAITLG; BAR();
  if (tid < 2) {
    float s = Wval[256] + bval[0];
    const float* pt = (const float*)ptlb;
    #pragma unroll
    for (int w8 = 0; w8 < 8; ++w8) s += pt[w8 * 4 + tid];
    out[(size_t)blockIdx.x * 2 + tid] = s;
  }
}

extern "C" void kernel_launch(void* const* d_in, const int* in_sizes, int n_in,
                              void* d_out, int out_size, void* d_ws, size_t ws_size,
                              hipStream_t stream) {
  (void)in_sizes; (void)n_in; (void)out_size; (void)ws_size;
  const float* obs  = (const float*)d_in[0];
  const float* Wemb = (const float*)d_in[1];
  const float* bemb = (const float*)d_in[2];
  const float* Wq   = (const float*)d_in[3];
  const float* bq   = (const float*)d_in[4];
  const float* Wk   = (const float*)d_in[5];
  const float* bk   = (const float*)d_in[6];
  const float* Wv   = (const float*)d_in[7];
  const float* bv   = (const float*)d_in[8];
  const float* Wo   = (const float*)d_in[9];
  const float* bo   = (const float*)d_in[10];
  const float* W1   = (const float*)d_in[11];
  const float* b1   = (const float*)d_in[12];
  const float* W2   = (const float*)d_in[13];
  const float* b2   = (const float*)d_in[14];
  const float* Wval = (const float*)d_in[15];
  const float* bval = (const float*)d_in[16];
  ushort_t* ws = (ushort_t*)d_ws;
  float* out = (float*)d_out;

  pack_weights<<<208, 256, 0, stream>>>(Wemb, Wq, Wk, Wv, Wo, W1, W2, ws);
  poca_fused<<<4096, 512, 0, stream>>>(obs, ws, bemb, bq, bk, bv, bo, b1, b2, Wval, bval, out);
}